// Round 20
// baseline (3206.036 us; speedup 1.0000x reference)
//
#include <hip/hip_runtime.h>
#include <stdint.h>

typedef unsigned short u16;
typedef short short8 __attribute__((ext_vector_type(8)));
typedef float f32x4 __attribute__((ext_vector_type(4)));
typedef int i32x4 __attribute__((ext_vector_type(4)));
typedef unsigned long long u64;

#define NT 512
#define NH 1024
#define G4H 4096
#define HS_ELEMS 33554432ull   // 64*512*1024

static __device__ __forceinline__ u16 f2bf(float f){
  union { float f; unsigned u; } v; v.f = f;
  unsigned r = v.u + 0x7fffu + ((v.u >> 16) & 1u);   // RNE
  return (u16)(r >> 16);
}
static __device__ __forceinline__ float bf2f(u16 s){
  union { unsigned u; float f; } v; v.u = ((unsigned)s) << 16;
  return v.f;
}

// ---------------- fp32 -> bf16 bulk convert ----------------
__global__ void cvt_kernel(const float* __restrict__ in, u16* __restrict__ out, int n8){
  int i = blockIdx.x*blockDim.x + threadIdx.x;
  int stride = gridDim.x*blockDim.x;
  for (; i < n8; i += stride){
    const float4* p = (const float4*)in;
    float4 a = p[2*i], b = p[2*i+1];
    short8 o;
    o[0]=(short)f2bf(a.x); o[1]=(short)f2bf(a.y); o[2]=(short)f2bf(a.z); o[3]=(short)f2bf(a.w);
    o[4]=(short)f2bf(b.x); o[5]=(short)f2bf(b.y); o[6]=(short)f2bf(b.z); o[7]=(short)f2bf(b.w);
    ((short8*)out)[i] = o;
  }
}

// ---------------- init h ring buffer + counters ----------------
__global__ void init_kernel(unsigned* __restrict__ hx, int* __restrict__ cnt){
  int i = blockIdx.x*blockDim.x + threadIdx.x;
  int stride = gridDim.x*blockDim.x;
  for (int k = i; k < 131072; k += stride) hx[k] = 0u;   // 512 KiB of bf16 zeros
  if (i < 256) cnt[i] = 0;
}

// ---------------- phase 1: xg = x @ w_ih^T + b  (bf16 MFMA, m97-style) ----------------
__global__ __launch_bounds__(256) void gemm_xg(
    const u16* __restrict__ A,     // x bf16 [32768][1024]
    const u16* __restrict__ Bw,    // w_ih bf16 [4096][1024]  (B^T layout)
    const float* __restrict__ bias,
    u16* __restrict__ C)           // xg bf16 [32768][4096]
{
  __shared__ u16 lA[128*64];
  __shared__ u16 lB[128*64];
  const int tid = threadIdx.x, lane = tid & 63, w = tid >> 6;
  int bid = blockIdx.x;
  int swz = (bid & 7)*1024 + (bid >> 3);     // XCD swizzle (8192 % 8 == 0, bijective)
  const int brow = swz >> 5;                 // 0..255
  const int bcol = swz & 31;                 // 0..31
  const int wr = (w >> 1)*64, wc = (w & 1)*64;
  f32x4 acc[4][4] = {};

  const int rA0 = brow*128 + w*32;
  const int rB0 = bcol*128 + w*32;
  for (int kt = 0; kt < 1024; kt += 64){
    const u16* gA = A  + (size_t)(rA0 + (lane>>3))*1024 + kt + (lane&7)*8;
    const u16* gB = Bw + (size_t)(rB0 + (lane>>3))*1024 + kt + (lane&7)*8;
#pragma unroll
    for (int c = 0; c < 4; c++){
      __builtin_amdgcn_global_load_lds(
        (const __attribute__((address_space(1))) void*)(gA + (size_t)c*8*1024),
        (__attribute__((address_space(3))) void*)&lA[(w*32 + c*8)*64], 16, 0, 0);
      __builtin_amdgcn_global_load_lds(
        (const __attribute__((address_space(1))) void*)(gB + (size_t)c*8*1024),
        (__attribute__((address_space(3))) void*)&lB[(w*32 + c*8)*64], 16, 0, 0);
    }
    __syncthreads();
#pragma unroll
    for (int kk = 0; kk < 2; kk++){
      short8 fa[4], fb[4];
#pragma unroll
      for (int i = 0; i < 4; i++){
        fa[i] = *(const short8*)&lA[(wr + i*16 + (lane&15))*64 + kk*32 + (lane>>4)*8];
        fb[i] = *(const short8*)&lB[(wc + i*16 + (lane&15))*64 + kk*32 + (lane>>4)*8];
      }
#pragma unroll
      for (int i = 0; i < 4; i++)
#pragma unroll
        for (int jj = 0; jj < 4; jj++)
          acc[i][jj] = __builtin_amdgcn_mfma_f32_16x16x32_bf16(fa[i], fb[jj], acc[i][jj], 0,0,0);
    }
    __syncthreads();
  }
  const int mb = brow*128 + wr + ((lane>>4)<<2);
  const int nb = bcol*128 + wc + (lane&15);
#pragma unroll
  for (int jj = 0; jj < 4; jj++){
    const int n = nb + jj*16;
    const float bv = bias[n];
#pragma unroll
    for (int i = 0; i < 4; i++){
#pragma unroll
      for (int reg = 0; reg < 4; reg++){
        int m = mb + i*16 + reg;
        C[(size_t)m*G4H + n] = f2bf(acc[i][jj][reg] + bv);
      }
    }
  }
}

// ---------------- phase 2: persistent recurrence (R19 + split-K half pipelining) ----------------
// Grid 128 x 512 threads = 4 batch-groups x 32 col-slice WGs (32 h-cols, 8 waves).
// Base = R19 (PASSED, 2.52ms). New: the group's h is consumed in TWO halves.
// K-chunk kk (h cols 32kk..32kk+31) is published by exactly WG j=kk, so:
//   lower WGs (j<16, cols 0..511)  signal cnt_lo after publish+ack;
//   upper WGs (j>=16, cols 512..1023) signal cnt_hi.
// Reader: poll cnt_lo>=16t -> barrier -> stage lower 16KB -> barrier ->
//   MFMA kk=0..15 -> poll cnt_hi>=16t (detect overlapped with lower MFMA) ->
//   barrier -> stage upper -> barrier -> MFMA kk=16..31 -> activations ->
//   publish -> barrier(ack) -> signal own half -> deferred hs/cs stores.
// Soundness: every WG polls BOTH counters every step (R13 lesson); each
// signal follows the signaler's FULL publish + intra-WG ack => entering step
// t implies all 32 WGs completed step t-1 => skew <= 1, ring depth 4 safe.
// No pre-poll speculative reads (that family is empirically dead on this HW).
__global__ __launch_bounds__(512, 2) void lstm_rec(
    const u16* __restrict__ whh,   // [4096][1024] bf16
    const u16* __restrict__ xg,    // [64*512][4096] bf16 (row b*512+t), bias included
    u16* __restrict__ hx,          // [4][4][32][64][8] bf16 (fragment order)
    int* cnt,                      // [4*64] ints: per group cnt_lo at +0, cnt_hi at +32
    float* __restrict__ hs,
    float* __restrict__ cs)
{
  __shared__ u16 lds_h[16384];     // 32 KiB: group h in fragment order [32][64][8]
  const int tid  = threadIdx.x;
  const int lane = tid & 63;
  const int w    = tid >> 6;          // wave 0..7
  const int bid  = blockIdx.x;
  const int g    = bid >> 5;          // batch group 0..3
  const int j    = bid & 31;          // col-slice 0..31 (== K-chunk this WG publishes)
  const int q    = (lane & 15) >> 2;  // gate type 0:i 1:f 2:g 3:o
  const int col  = j*32 + w*4 + (lane & 3);   // h column 0..1023
  const int Gr   = q*1024 + col;              // gate row 0..4095
  const int mloc = (lane >> 4) * 4;           // batch-in-group base

  // ---- weights -> regs (R6-proven; compiler parks them in AGPRs) ----
  i32x4 wq[32];
  {
    const i32x4* wp = (const i32x4*)(whh + (size_t)Gr*1024 + ((lane>>4)*8));
#pragma unroll
    for (int kk = 0; kk < 32; kk++) wq[kk] = wp[kk*4];
#pragma unroll
    for (int kk = 0; kk < 32; kk++) asm volatile("" : "+v"(wq[kk]));
  }

  float c_st[4] = {0.f,0.f,0.f,0.f};
  int* cnt_lo = cnt + g*64;
  int* cnt_hi = cnt + g*64 + 32;
  int* mycnt  = (j < 16) ? cnt_lo : cnt_hi;

  for (int t = 0; t < NT; t++){
    // xg prefetch (HBM, independent of h) — hides under the lower poll+stage
    float xv[4];
#pragma unroll
    for (int reg = 0; reg < 4; reg++){
      int b = g*16 + mloc + reg;
      xv[reg] = bf2f(xg[((size_t)b*NT + t)*G4H + Gr]);
    }
    const u64* hb64 = (const u64*)(hx + ((size_t)(((t+3)&3)*4 + g)) * 16384);

    // ---- LOWER half: poll -> stage -> MFMA kk=0..15 ----
    if (t > 0){
      if (tid == 0){
        const int need = t * 16;
        while (__hip_atomic_load(cnt_lo, __ATOMIC_RELAXED, __HIP_MEMORY_SCOPE_AGENT) < need)
          __builtin_amdgcn_s_sleep(1);
      }
      __syncthreads();
    }
#pragma unroll
    for (int k = 0; k < 4; k++){
      int W = tid + 512*k;               // u64 index 0..2047 = lower 16 KiB
      u64 v = __hip_atomic_load(hb64 + W, __ATOMIC_RELAXED, __HIP_MEMORY_SCOPE_AGENT);
      *(u64*)&lds_h[W*4] = v;
    }
    __syncthreads();

    f32x4 accv[4];
    accv[0] = (f32x4){xv[0], xv[1], xv[2], xv[3]};
    accv[1] = (f32x4){0.f,0.f,0.f,0.f};
    accv[2] = accv[1]; accv[3] = accv[1];
#pragma unroll
    for (int kk = 0; kk < 16; kk++){
      short8 av = *(const short8*)&lds_h[(kk*64 + lane)*8];
      short8 bv = __builtin_bit_cast(short8, wq[kk]);
      accv[kk & 3] = __builtin_amdgcn_mfma_f32_16x16x32_bf16(av, bv, accv[kk & 3], 0,0,0);
    }

    // ---- UPPER half: poll (detect overlapped lower MFMA) -> stage -> MFMA ----
    if (t > 0){
      if (tid == 0){
        const int need = t * 16;
        while (__hip_atomic_load(cnt_hi, __ATOMIC_RELAXED, __HIP_MEMORY_SCOPE_AGENT) < need)
          __builtin_amdgcn_s_sleep(1);
      }
      __syncthreads();
    }
#pragma unroll
    for (int k = 0; k < 4; k++){
      int W = 2048 + tid + 512*k;        // u64 index 2048..4095 = upper 16 KiB
      u64 v = __hip_atomic_load(hb64 + W, __ATOMIC_RELAXED, __HIP_MEMORY_SCOPE_AGENT);
      *(u64*)&lds_h[W*4] = v;
    }
    __syncthreads();
#pragma unroll
    for (int kk = 16; kk < 32; kk++){
      short8 av = *(const short8*)&lds_h[(kk*64 + lane)*8];
      short8 bv = __builtin_bit_cast(short8, wq[kk]);
      accv[kk & 3] = __builtin_amdgcn_mfma_f32_16x16x32_bf16(av, bv, accv[kk & 3], 0,0,0);
    }
    f32x4 gv = (accv[0] + accv[1]) + (accv[2] + accv[3]);

    // ---- activations; publish h, ack, signal own half, THEN deferred stores ----
    u16* wbuf = hx + ((size_t)((t&3)*4 + g)) * 16384;
    float hnv[4], cnv[4];
#pragma unroll
    for (int reg = 0; reg < 4; reg++){
      float xg_ = gv[reg];
      float sig = 1.f / (1.f + __expf(-xg_));
      float th  = 1.f - 2.f / (1.f + __expf(2.f*xg_));
      float a   = (q == 2) ? th : sig;
      float v4  = __shfl_xor(a, 4);
      float v8  = __shfl_xor(a, 8);
      float v12 = __shfl_xor(a, 12);
      float iv  = (q==0)?a :(q==1)?v4:(q==2)?v8:v12;
      float fv  = (q==1)?a :(q==0)?v4:(q==3)?v8:v12;
      float gg  = (q==2)?a :(q==3)?v4:(q==0)?v8:v12;
      float ov  = (q==3)?a :(q==2)?v4:(q==1)?v8:v12;
      float cn  = fv*c_st[reg] + iv*gg;
      c_st[reg] = cn;
      float tc  = 1.f - 2.f / (1.f + __expf(2.f*cn));
      float hn  = ov * tc;
      hnv[reg] = hn; cnv[reg] = cn;
      // publish h via paired u32 sc1 atomic store (write-through to L3)
      float hp = __shfl_xor(hn, 1);          // partner column's h
      if (q == 0 && (lane & 1) == 0){
        unsigned word = (unsigned)f2bf(hn) | ((unsigned)f2bf(hp) << 16);
        int sub = ((col & 31) >> 3)*16 + (mloc + reg);
        int idx16 = ((col >> 5)*64 + sub)*8 + (col & 7);   // even
        __hip_atomic_store((unsigned*)(wbuf + idx16), word,
                           __ATOMIC_RELAXED, __HIP_MEMORY_SCOPE_AGENT);
      }
    }
    __syncthreads();   // drains ONLY the publish stores (outputs not yet issued)
    if (tid == 0)
      __hip_atomic_fetch_add(mycnt, 1, __ATOMIC_RELAXED, __HIP_MEMORY_SCOPE_AGENT);
    // deferred output stores — off the signal path; acks drain next step
#pragma unroll
    for (int reg = 0; reg < 4; reg++){
      int b = g*16 + mloc + reg;
      size_t oidx = ((size_t)b*NT + t)*NH + col;
      if (q == 1) __builtin_nontemporal_store(hnv[reg], &hs[oidx]);
      if (q == 2) __builtin_nontemporal_store(cnv[reg], &cs[oidx]);
    }
  }
}

extern "C" void kernel_launch(void* const* d_in, const int* in_sizes, int n_in,
                              void* d_out, int out_size, void* d_ws, size_t ws_size,
                              hipStream_t stream){
  const float* x    = (const float*)d_in[0];
  const float* wih  = (const float*)d_in[1];
  const float* whh  = (const float*)d_in[2];
  const float* bias = (const float*)d_in[3];
  float* hs = (float*)d_out;
  float* cs = hs + HS_ELEMS;
  char* ws = (char*)d_ws;
  // ws layout (~337 MiB)
  u16* xg   = (u16*)(ws + 0);              // 256 MiB
  u16* xb   = (u16*)(ws + 268435456ull);   // 64 MiB
  u16* wihb = (u16*)(ws + 335544320ull);   // 8 MiB
  u16* whhb = (u16*)(ws + 343932928ull);   // 8 MiB
  u16* hx   = (u16*)(ws + 352321536ull);   // 512 KiB ring
  int* cnt  = (int*)(ws + 352845824ull);   // 1 KiB

  cvt_kernel<<<2048, 256, 0, stream>>>(x,   xb,   33554432/8);
  cvt_kernel<<<512,  256, 0, stream>>>(wih, wihb, 4194304/8);
  cvt_kernel<<<512,  256, 0, stream>>>(whh, whhb, 4194304/8);
  init_kernel<<<64,  256, 0, stream>>>((unsigned*)hx, cnt);
  gemm_xg<<<8192, 256, 0, stream>>>(xb, wihb, bias, xg);

  const u16* whhb_c = whhb; const u16* xg_c = xg;
  u16* hx_p = hx; int* cnt_p = cnt; float* hs_p = hs; float* cs_p = cs;
  void* args[6];
  args[0] = (void*)&whhb_c;
  args[1] = (void*)&xg_c;
  args[2] = (void*)&hx_p;
  args[3] = (void*)&cnt_p;
  args[4] = (void*)&cs_p;   // placeholder overwritten below (keep arg order correct)
  args[4] = (void*)&hs_p;
  args[5] = (void*)&cs_p;
  hipLaunchCooperativeKernel((const void*)lstm_rec, dim3(128), dim3(512), args, 0, stream);
}

// Round 21
// 3016.053 us; speedup vs baseline: 1.0630x; 1.0630x over previous
//
#include <hip/hip_runtime.h>
#include <stdint.h>

typedef unsigned short u16;
typedef short short8 __attribute__((ext_vector_type(8)));
typedef float f32x4 __attribute__((ext_vector_type(4)));
typedef int i32x4 __attribute__((ext_vector_type(4)));
typedef unsigned long long u64;

#define NT 512
#define NH 1024
#define G4H 4096
#define HS_ELEMS 33554432ull   // 64*512*1024

static __device__ __forceinline__ u16 f2bf(float f){
  union { float f; unsigned u; } v; v.f = f;
  unsigned r = v.u + 0x7fffu + ((v.u >> 16) & 1u);   // RNE
  return (u16)(r >> 16);
}
static __device__ __forceinline__ float bf2f(u16 s){
  union { unsigned u; float f; } v; v.u = ((unsigned)s) << 16;
  return v.f;
}

// ---------------- fp32 -> bf16 bulk convert ----------------
__global__ void cvt_kernel(const float* __restrict__ in, u16* __restrict__ out, int n8){
  int i = blockIdx.x*blockDim.x + threadIdx.x;
  int stride = gridDim.x*blockDim.x;
  for (; i < n8; i += stride){
    const float4* p = (const float4*)in;
    float4 a = p[2*i], b = p[2*i+1];
    short8 o;
    o[0]=(short)f2bf(a.x); o[1]=(short)f2bf(a.y); o[2]=(short)f2bf(a.z); o[3]=(short)f2bf(a.w);
    o[4]=(short)f2bf(b.x); o[5]=(short)f2bf(b.y); o[6]=(short)f2bf(b.z); o[7]=(short)f2bf(b.w);
    ((short8*)out)[i] = o;
  }
}

// ---------------- init h ring buffer + counters ----------------
__global__ void init_kernel(unsigned* __restrict__ hx, int* __restrict__ cnt){
  int i = blockIdx.x*blockDim.x + threadIdx.x;
  int stride = gridDim.x*blockDim.x;
  for (int k = i; k < 131072; k += stride) hx[k] = 0u;   // 512 KiB of bf16 zeros
  if (i < 256) cnt[i] = 0;
}

// ---------------- phase 1: xg = x @ w_ih^T + b  (bf16 MFMA, m97-style) ----------------
__global__ __launch_bounds__(256) void gemm_xg(
    const u16* __restrict__ A,     // x bf16 [32768][1024]
    const u16* __restrict__ Bw,    // w_ih bf16 [4096][1024]  (B^T layout)
    const float* __restrict__ bias,
    u16* __restrict__ C)           // xg bf16 [32768][4096]
{
  __shared__ u16 lA[128*64];
  __shared__ u16 lB[128*64];
  const int tid = threadIdx.x, lane = tid & 63, w = tid >> 6;
  int bid = blockIdx.x;
  int swz = (bid & 7)*1024 + (bid >> 3);     // XCD swizzle (8192 % 8 == 0, bijective)
  const int brow = swz >> 5;                 // 0..255
  const int bcol = swz & 31;                 // 0..31
  const int wr = (w >> 1)*64, wc = (w & 1)*64;
  f32x4 acc[4][4] = {};

  const int rA0 = brow*128 + w*32;
  const int rB0 = bcol*128 + w*32;
  for (int kt = 0; kt < 1024; kt += 64){
    const u16* gA = A  + (size_t)(rA0 + (lane>>3))*1024 + kt + (lane&7)*8;
    const u16* gB = Bw + (size_t)(rB0 + (lane>>3))*1024 + kt + (lane&7)*8;
#pragma unroll
    for (int c = 0; c < 4; c++){
      __builtin_amdgcn_global_load_lds(
        (const __attribute__((address_space(1))) void*)(gA + (size_t)c*8*1024),
        (__attribute__((address_space(3))) void*)&lA[(w*32 + c*8)*64], 16, 0, 0);
      __builtin_amdgcn_global_load_lds(
        (const __attribute__((address_space(1))) void*)(gB + (size_t)c*8*1024),
        (__attribute__((address_space(3))) void*)&lB[(w*32 + c*8)*64], 16, 0, 0);
    }
    __syncthreads();
#pragma unroll
    for (int kk = 0; kk < 2; kk++){
      short8 fa[4], fb[4];
#pragma unroll
      for (int i = 0; i < 4; i++){
        fa[i] = *(const short8*)&lA[(wr + i*16 + (lane&15))*64 + kk*32 + (lane>>4)*8];
        fb[i] = *(const short8*)&lB[(wc + i*16 + (lane&15))*64 + kk*32 + (lane>>4)*8];
      }
#pragma unroll
      for (int i = 0; i < 4; i++)
#pragma unroll
        for (int jj = 0; jj < 4; jj++)
          acc[i][jj] = __builtin_amdgcn_mfma_f32_16x16x32_bf16(fa[i], fb[jj], acc[i][jj], 0,0,0);
    }
    __syncthreads();
  }
  const int mb = brow*128 + wr + ((lane>>4)<<2);
  const int nb = bcol*128 + wc + (lane&15);
#pragma unroll
  for (int jj = 0; jj < 4; jj++){
    const int n = nb + jj*16;
    const float bv = bias[n];
#pragma unroll
    for (int i = 0; i < 4; i++){
#pragma unroll
      for (int reg = 0; reg < 4; reg++){
        int m = mb + i*16 + reg;
        C[(size_t)m*G4H + n] = f2bf(acc[i][jj][reg] + bv);
      }
    }
  }
}

// ---------------- phase 2: persistent recurrence (R19 FINAL: R14 protocol, 32 WGs/group) ----------------
// Grid 128 x 512 threads = 4 batch-groups x 32 col-slice WGs (32 h-cols each,
// 8 waves). Best-measured configuration (2.52ms): signals/step 32 per group,
// straggler pool max-of-32, publish-ack aggregated over 8 waves per intra-WG
// barrier. __launch_bounds__(512,2) -> 2 waves/SIMD -> 256 VGPR/wave budget;
// 128 weight regs + ~104 working set fits (R18: 1024-thr WG caps budget at
// 128 and kills weight residency; R20: finer split-K signaling adds RTTs and
// regresses). Protocol (R8/R14-proven, fence-free):
//   reader: tid0 relaxed poll (cnt >= 32t) -> barrier -> sc1 u64 stage -> LDS
//           -> barrier;
//   writer: publish h via paired sc1 u32 stores -> barrier (per-wave vmcnt0 =
//           publishes acked) -> tid0 relaxed fetch_add -> deferred hs/cs.
// Counter induction: entering t requires cnt >= 32t => all 32 WGs signaled
// step t-1 (every WG polls every step — the R13 soundness lesson). Ring
// depth 4 => race-free. No pre-poll speculative reads (family empirically
// dead on this HW: R11/R12/R13/R15/R16).
__global__ __launch_bounds__(512, 2) void lstm_rec(
    const u16* __restrict__ whh,   // [4096][1024] bf16
    const u16* __restrict__ xg,    // [64*512][4096] bf16 (row b*512+t), bias included
    u16* __restrict__ hx,          // [4][4][32][64][8] bf16 (fragment order)
    int* cnt,                      // [4*64] (256B-spaced per group)
    float* __restrict__ hs,
    float* __restrict__ cs)
{
  __shared__ u16 lds_h[16384];     // 32 KiB: group h in fragment order [32][64][8]
  const int tid  = threadIdx.x;
  const int lane = tid & 63;
  const int w    = tid >> 6;          // wave 0..7
  const int bid  = blockIdx.x;
  const int g    = bid >> 5;          // batch group 0..3
  const int j    = bid & 31;          // col-slice 0..31
  const int q    = (lane & 15) >> 2;  // gate type 0:i 1:f 2:g 3:o
  const int col  = j*32 + w*4 + (lane & 3);   // h column 0..1023
  const int Gr   = q*1024 + col;              // gate row 0..4095
  const int mloc = (lane >> 4) * 4;           // batch-in-group base

  // ---- weights -> regs (R6-proven; compiler parks them in AGPRs) ----
  i32x4 wq[32];
  {
    const i32x4* wp = (const i32x4*)(whh + (size_t)Gr*1024 + ((lane>>4)*8));
#pragma unroll
    for (int kk = 0; kk < 32; kk++) wq[kk] = wp[kk*4];
#pragma unroll
    for (int kk = 0; kk < 32; kk++) asm volatile("" : "+v"(wq[kk]));
  }

  float c_st[4] = {0.f,0.f,0.f,0.f};
  int* cntg = cnt + g*64;

  for (int t = 0; t < NT; t++){
    // xg prefetch (independent of h) — hides HBM latency under the poll
    float xv[4];
#pragma unroll
    for (int reg = 0; reg < 4; reg++){
      int b = g*16 + mloc + reg;
      xv[reg] = bf2f(xg[((size_t)b*NT + t)*G4H + Gr]);
    }
    // ---- wait for h(t-1): leader relaxed poll -> barrier ----
    if (t > 0){
      if (tid == 0){
        const int need = t * 32;
        while (__hip_atomic_load(cntg, __ATOMIC_RELAXED, __HIP_MEMORY_SCOPE_AGENT) < need)
          __builtin_amdgcn_s_sleep(1);
      }
      __syncthreads();
    }
    // ---- stage h(t-1) -> LDS via sc1 atomic u64 loads (bypass stale L2) ----
    const u64* hb64 = (const u64*)(hx + ((size_t)(((t+3)&3)*4 + g)) * 16384);
#pragma unroll
    for (int k = 0; k < 8; k++){
      int W = tid + 512*k;
      u64 v = __hip_atomic_load(hb64 + W, __ATOMIC_RELAXED, __HIP_MEMORY_SCOPE_AGENT);
      *(u64*)&lds_h[W*4] = v;
    }
    __syncthreads();

    // ---- gates = xg + h @ w_hh^T : 32 builtin MFMAs ----
    f32x4 accv[4];
    accv[0] = (f32x4){xv[0], xv[1], xv[2], xv[3]};
    accv[1] = (f32x4){0.f,0.f,0.f,0.f};
    accv[2] = accv[1]; accv[3] = accv[1];
#pragma unroll
    for (int kk = 0; kk < 32; kk++){
      short8 av = *(const short8*)&lds_h[(kk*64 + lane)*8];
      short8 bv = __builtin_bit_cast(short8, wq[kk]);
      accv[kk & 3] = __builtin_amdgcn_mfma_f32_16x16x32_bf16(av, bv, accv[kk & 3], 0,0,0);
    }
    f32x4 gv = (accv[0] + accv[1]) + (accv[2] + accv[3]);

    // ---- activations; publish h, ack, signal, THEN deferred output stores ----
    u16* wbuf = hx + ((size_t)((t&3)*4 + g)) * 16384;
    float hnv[4], cnv[4];
#pragma unroll
    for (int reg = 0; reg < 4; reg++){
      float xg_ = gv[reg];
      float sig = 1.f / (1.f + __expf(-xg_));
      float th  = 1.f - 2.f / (1.f + __expf(2.f*xg_));
      float a   = (q == 2) ? th : sig;
      float v4  = __shfl_xor(a, 4);
      float v8  = __shfl_xor(a, 8);
      float v12 = __shfl_xor(a, 12);
      float iv  = (q==0)?a :(q==1)?v4:(q==2)?v8:v12;
      float fv  = (q==1)?a :(q==0)?v4:(q==3)?v8:v12;
      float gg  = (q==2)?a :(q==3)?v4:(q==0)?v8:v12;
      float ov  = (q==3)?a :(q==2)?v4:(q==1)?v8:v12;
      float cn  = fv*c_st[reg] + iv*gg;
      c_st[reg] = cn;
      float tc  = 1.f - 2.f / (1.f + __expf(2.f*cn));
      float hn  = ov * tc;
      hnv[reg] = hn; cnv[reg] = cn;
      // publish h via paired u32 sc1 atomic store (write-through to L3)
      float hp = __shfl_xor(hn, 1);          // partner column's h
      if (q == 0 && (lane & 1) == 0){
        unsigned word = (unsigned)f2bf(hn) | ((unsigned)f2bf(hp) << 16);
        int sub = ((col & 31) >> 3)*16 + (mloc + reg);
        int idx16 = ((col >> 5)*64 + sub)*8 + (col & 7);   // even
        __hip_atomic_store((unsigned*)(wbuf + idx16), word,
                           __ATOMIC_RELAXED, __HIP_MEMORY_SCOPE_AGENT);
      }
    }
    __syncthreads();   // drains ONLY the publish stores (outputs not yet issued)
    if (tid == 0)
      __hip_atomic_fetch_add(cntg, 1, __ATOMIC_RELAXED, __HIP_MEMORY_SCOPE_AGENT);
    // deferred output stores — off the signal path; acks drain next step
#pragma unroll
    for (int reg = 0; reg < 4; reg++){
      int b = g*16 + mloc + reg;
      size_t oidx = ((size_t)b*NT + t)*NH + col;
      if (q == 1) __builtin_nontemporal_store(hnv[reg], &hs[oidx]);
      if (q == 2) __builtin_nontemporal_store(cnv[reg], &cs[oidx]);
    }
  }
}

extern "C" void kernel_launch(void* const* d_in, const int* in_sizes, int n_in,
                              void* d_out, int out_size, void* d_ws, size_t ws_size,
                              hipStream_t stream){
  const float* x    = (const float*)d_in[0];
  const float* wih  = (const float*)d_in[1];
  const float* whh  = (const float*)d_in[2];
  const float* bias = (const float*)d_in[3];
  float* hs = (float*)d_out;
  float* cs = hs + HS_ELEMS;
  char* ws = (char*)d_ws;
  // ws layout (~337 MiB)
  u16* xg   = (u16*)(ws + 0);              // 256 MiB
  u16* xb   = (u16*)(ws + 268435456ull);   // 64 MiB
  u16* wihb = (u16*)(ws + 335544320ull);   // 8 MiB
  u16* whhb = (u16*)(ws + 343932928ull);   // 8 MiB
  u16* hx   = (u16*)(ws + 352321536ull);   // 512 KiB ring
  int* cnt  = (int*)(ws + 352845824ull);   // 1 KiB

  cvt_kernel<<<2048, 256, 0, stream>>>(x,   xb,   33554432/8);
  cvt_kernel<<<512,  256, 0, stream>>>(wih, wihb, 4194304/8);
  cvt_kernel<<<512,  256, 0, stream>>>(whh, whhb, 4194304/8);
  init_kernel<<<64,  256, 0, stream>>>((unsigned*)hx, cnt);
  gemm_xg<<<8192, 256, 0, stream>>>(xb, wihb, bias, xg);

  const u16* whhb_c = whhb; const u16* xg_c = xg;
  u16* hx_p = hx; int* cnt_p = cnt; float* hs_p = hs; float* cs_p = cs;
  void* args[6];
  args[0] = (void*)&whhb_c;
  args[1] = (void*)&xg_c;
  args[2] = (void*)&hx_p;
  args[3] = (void*)&cnt_p;
  args[4] = (void*)&hs_p;
  args[5] = (void*)&cs_p;
  hipLaunchCooperativeKernel((const void*)lstm_rec, dim3(128), dim3(512), args, 0, stream);
}

// Round 22
// 3015.666 us; speedup vs baseline: 1.0631x; 1.0001x over previous
//
#include <hip/hip_runtime.h>
#include <stdint.h>

typedef unsigned short u16;
typedef short short8 __attribute__((ext_vector_type(8)));
typedef float f32x4 __attribute__((ext_vector_type(4)));
typedef int i32x4 __attribute__((ext_vector_type(4)));
typedef unsigned long long u64;

#define NT 512
#define NH 1024
#define G4H 4096
#define HS_ELEMS 33554432ull   // 64*512*1024

static __device__ __forceinline__ u16 f2bf(float f){
  union { float f; unsigned u; } v; v.f = f;
  unsigned r = v.u + 0x7fffu + ((v.u >> 16) & 1u);   // RNE
  return (u16)(r >> 16);
}
static __device__ __forceinline__ float bf2f(u16 s){
  union { unsigned u; float f; } v; v.u = ((unsigned)s) << 16;
  return v.f;
}
static __device__ __forceinline__ void cvt8(const float* __restrict__ in, u16* __restrict__ out, int k){
  const float4* p = (const float4*)in;
  float4 a = p[2*k], b = p[2*k+1];
  short8 o;
  o[0]=(short)f2bf(a.x); o[1]=(short)f2bf(a.y); o[2]=(short)f2bf(a.z); o[3]=(short)f2bf(a.w);
  o[4]=(short)f2bf(b.x); o[5]=(short)f2bf(b.y); o[6]=(short)f2bf(b.z); o[7]=(short)f2bf(b.w);
  ((short8*)out)[k] = o;
}

// ---------------- fused prologue: cvt x/wih/whh + init ring + counters ----------------
__global__ void prep_kernel(const float* __restrict__ x,
                            const float* __restrict__ wih,
                            const float* __restrict__ whh,
                            u16* __restrict__ xb,
                            u16* __restrict__ wihb,
                            u16* __restrict__ whhb,
                            unsigned* __restrict__ hx,
                            int* __restrict__ cnt){
  int i = blockIdx.x*blockDim.x + threadIdx.x;
  int stride = gridDim.x*blockDim.x;
  for (int k = i; k < 4194304; k += stride) cvt8(x,   xb,   k);   // 33.5M floats
  for (int k = i; k < 524288;  k += stride) cvt8(wih, wihb, k);   // 4.2M floats
  for (int k = i; k < 524288;  k += stride) cvt8(whh, whhb, k);   // 4.2M floats
  for (int k = i; k < 131072;  k += stride) hx[k] = 0u;           // 512 KiB ring zeros
  if (i < 256) cnt[i] = 0;
}

// ---------------- phase 1: xg = x @ w_ih^T + b  (bf16 MFMA, m97-style) ----------------
__global__ __launch_bounds__(256) void gemm_xg(
    const u16* __restrict__ A,     // x bf16 [32768][1024]
    const u16* __restrict__ Bw,    // w_ih bf16 [4096][1024]  (B^T layout)
    const float* __restrict__ bias,
    u16* __restrict__ C)           // xg bf16 [32768][4096]
{
  __shared__ u16 lA[128*64];
  __shared__ u16 lB[128*64];
  const int tid = threadIdx.x, lane = tid & 63, w = tid >> 6;
  int bid = blockIdx.x;
  int swz = (bid & 7)*1024 + (bid >> 3);     // XCD swizzle (8192 % 8 == 0, bijective)
  const int brow = swz >> 5;                 // 0..255
  const int bcol = swz & 31;                 // 0..31
  const int wr = (w >> 1)*64, wc = (w & 1)*64;
  f32x4 acc[4][4] = {};

  const int rA0 = brow*128 + w*32;
  const int rB0 = bcol*128 + w*32;
  for (int kt = 0; kt < 1024; kt += 64){
    const u16* gA = A  + (size_t)(rA0 + (lane>>3))*1024 + kt + (lane&7)*8;
    const u16* gB = Bw + (size_t)(rB0 + (lane>>3))*1024 + kt + (lane&7)*8;
#pragma unroll
    for (int c = 0; c < 4; c++){
      __builtin_amdgcn_global_load_lds(
        (const __attribute__((address_space(1))) void*)(gA + (size_t)c*8*1024),
        (__attribute__((address_space(3))) void*)&lA[(w*32 + c*8)*64], 16, 0, 0);
      __builtin_amdgcn_global_load_lds(
        (const __attribute__((address_space(1))) void*)(gB + (size_t)c*8*1024),
        (__attribute__((address_space(3))) void*)&lB[(w*32 + c*8)*64], 16, 0, 0);
    }
    __syncthreads();
#pragma unroll
    for (int kk = 0; kk < 2; kk++){
      short8 fa[4], fb[4];
#pragma unroll
      for (int i = 0; i < 4; i++){
        fa[i] = *(const short8*)&lA[(wr + i*16 + (lane&15))*64 + kk*32 + (lane>>4)*8];
        fb[i] = *(const short8*)&lB[(wc + i*16 + (lane&15))*64 + kk*32 + (lane>>4)*8];
      }
#pragma unroll
      for (int i = 0; i < 4; i++)
#pragma unroll
        for (int jj = 0; jj < 4; jj++)
          acc[i][jj] = __builtin_amdgcn_mfma_f32_16x16x32_bf16(fa[i], fb[jj], acc[i][jj], 0,0,0);
    }
    __syncthreads();
  }
  const int mb = brow*128 + wr + ((lane>>4)<<2);
  const int nb = bcol*128 + wc + (lane&15);
#pragma unroll
  for (int jj = 0; jj < 4; jj++){
    const int n = nb + jj*16;
    const float bv = bias[n];
#pragma unroll
    for (int i = 0; i < 4; i++){
#pragma unroll
      for (int reg = 0; reg < 4; reg++){
        int m = mb + i*16 + reg;
        C[(size_t)m*G4H + n] = f2bf(acc[i][jj][reg] + bv);
      }
    }
  }
}

// ---------------- phase 2: persistent recurrence (R19/R21 FINAL, byte-identical) ----------------
// Grid 128 x 512 threads = 4 batch-groups x 32 col-slice WGs (32 h-cols each,
// 8 waves). Best-measured configuration (2.52ms). __launch_bounds__(512,2) ->
// 256 VGPR/wave budget; 128 weight regs + ~104 working set fits.
// Protocol (R8/R14-proven, fence-free):
//   reader: tid0 relaxed poll (cnt >= 32t) -> barrier -> sc1 u64 stage -> LDS
//           -> barrier;
//   writer: publish h via paired sc1 u32 stores -> barrier (per-wave vmcnt0 =
//           publishes acked) -> tid0 relaxed fetch_add -> deferred hs/cs.
// Counter induction: entering t requires cnt >= 32t => all 32 WGs signaled
// step t-1 (every WG polls every step). Ring depth 4 => race-free.
// Step time == structural chain: ack + signal + detect + stage + 3 barriers
// + compute ~ 4.8us vs 4.9us measured — latency-bound floor of this family.
__global__ __launch_bounds__(512, 2) void lstm_rec(
    const u16* __restrict__ whh,   // [4096][1024] bf16
    const u16* __restrict__ xg,    // [64*512][4096] bf16 (row b*512+t), bias included
    u16* __restrict__ hx,          // [4][4][32][64][8] bf16 (fragment order)
    int* cnt,                      // [4*64] (256B-spaced per group)
    float* __restrict__ hs,
    float* __restrict__ cs)
{
  __shared__ u16 lds_h[16384];     // 32 KiB: group h in fragment order [32][64][8]
  const int tid  = threadIdx.x;
  const int lane = tid & 63;
  const int w    = tid >> 6;          // wave 0..7
  const int bid  = blockIdx.x;
  const int g    = bid >> 5;          // batch group 0..3
  const int j    = bid & 31;          // col-slice 0..31
  const int q    = (lane & 15) >> 2;  // gate type 0:i 1:f 2:g 3:o
  const int col  = j*32 + w*4 + (lane & 3);   // h column 0..1023
  const int Gr   = q*1024 + col;              // gate row 0..4095
  const int mloc = (lane >> 4) * 4;           // batch-in-group base

  // ---- weights -> regs (R6-proven; compiler parks them in AGPRs) ----
  i32x4 wq[32];
  {
    const i32x4* wp = (const i32x4*)(whh + (size_t)Gr*1024 + ((lane>>4)*8));
#pragma unroll
    for (int kk = 0; kk < 32; kk++) wq[kk] = wp[kk*4];
#pragma unroll
    for (int kk = 0; kk < 32; kk++) asm volatile("" : "+v"(wq[kk]));
  }

  float c_st[4] = {0.f,0.f,0.f,0.f};
  int* cntg = cnt + g*64;

  for (int t = 0; t < NT; t++){
    // xg prefetch (independent of h) — hides HBM latency under the poll
    float xv[4];
#pragma unroll
    for (int reg = 0; reg < 4; reg++){
      int b = g*16 + mloc + reg;
      xv[reg] = bf2f(xg[((size_t)b*NT + t)*G4H + Gr]);
    }
    // ---- wait for h(t-1): leader relaxed poll -> barrier ----
    if (t > 0){
      if (tid == 0){
        const int need = t * 32;
        while (__hip_atomic_load(cntg, __ATOMIC_RELAXED, __HIP_MEMORY_SCOPE_AGENT) < need)
          __builtin_amdgcn_s_sleep(1);
      }
      __syncthreads();
    }
    // ---- stage h(t-1) -> LDS via sc1 atomic u64 loads (bypass stale L2) ----
    const u64* hb64 = (const u64*)(hx + ((size_t)(((t+3)&3)*4 + g)) * 16384);
#pragma unroll
    for (int k = 0; k < 8; k++){
      int W = tid + 512*k;
      u64 v = __hip_atomic_load(hb64 + W, __ATOMIC_RELAXED, __HIP_MEMORY_SCOPE_AGENT);
      *(u64*)&lds_h[W*4] = v;
    }
    __syncthreads();

    // ---- gates = xg + h @ w_hh^T : 32 builtin MFMAs ----
    f32x4 accv[4];
    accv[0] = (f32x4){xv[0], xv[1], xv[2], xv[3]};
    accv[1] = (f32x4){0.f,0.f,0.f,0.f};
    accv[2] = accv[1]; accv[3] = accv[1];
#pragma unroll
    for (int kk = 0; kk < 32; kk++){
      short8 av = *(const short8*)&lds_h[(kk*64 + lane)*8];
      short8 bv = __builtin_bit_cast(short8, wq[kk]);
      accv[kk & 3] = __builtin_amdgcn_mfma_f32_16x16x32_bf16(av, bv, accv[kk & 3], 0,0,0);
    }
    f32x4 gv = (accv[0] + accv[1]) + (accv[2] + accv[3]);

    // ---- activations; publish h, ack, signal, THEN deferred output stores ----
    u16* wbuf = hx + ((size_t)((t&3)*4 + g)) * 16384;
    float hnv[4], cnv[4];
#pragma unroll
    for (int reg = 0; reg < 4; reg++){
      float xg_ = gv[reg];
      float sig = 1.f / (1.f + __expf(-xg_));
      float th  = 1.f - 2.f / (1.f + __expf(2.f*xg_));
      float a   = (q == 2) ? th : sig;
      float v4  = __shfl_xor(a, 4);
      float v8  = __shfl_xor(a, 8);
      float v12 = __shfl_xor(a, 12);
      float iv  = (q==0)?a :(q==1)?v4:(q==2)?v8:v12;
      float fv  = (q==1)?a :(q==0)?v4:(q==3)?v8:v12;
      float gg  = (q==2)?a :(q==3)?v4:(q==0)?v8:v12;
      float ov  = (q==3)?a :(q==2)?v4:(q==1)?v8:v12;
      float cn  = fv*c_st[reg] + iv*gg;
      c_st[reg] = cn;
      float tc  = 1.f - 2.f / (1.f + __expf(2.f*cn));
      float hn  = ov * tc;
      hnv[reg] = hn; cnv[reg] = cn;
      // publish h via paired u32 sc1 atomic store (write-through to L3)
      float hp = __shfl_xor(hn, 1);          // partner column's h
      if (q == 0 && (lane & 1) == 0){
        unsigned word = (unsigned)f2bf(hn) | ((unsigned)f2bf(hp) << 16);
        int sub = ((col & 31) >> 3)*16 + (mloc + reg);
        int idx16 = ((col >> 5)*64 + sub)*8 + (col & 7);   // even
        __hip_atomic_store((unsigned*)(wbuf + idx16), word,
                           __ATOMIC_RELAXED, __HIP_MEMORY_SCOPE_AGENT);
      }
    }
    __syncthreads();   // drains ONLY the publish stores (outputs not yet issued)
    if (tid == 0)
      __hip_atomic_fetch_add(cntg, 1, __ATOMIC_RELAXED, __HIP_MEMORY_SCOPE_AGENT);
    // deferred output stores — off the signal path; acks drain next step
#pragma unroll
    for (int reg = 0; reg < 4; reg++){
      int b = g*16 + mloc + reg;
      size_t oidx = ((size_t)b*NT + t)*NH + col;
      if (q == 1) __builtin_nontemporal_store(hnv[reg], &hs[oidx]);
      if (q == 2) __builtin_nontemporal_store(cnv[reg], &cs[oidx]);
    }
  }
}

extern "C" void kernel_launch(void* const* d_in, const int* in_sizes, int n_in,
                              void* d_out, int out_size, void* d_ws, size_t ws_size,
                              hipStream_t stream){
  const float* x    = (const float*)d_in[0];
  const float* wih  = (const float*)d_in[1];
  const float* whh  = (const float*)d_in[2];
  const float* bias = (const float*)d_in[3];
  float* hs = (float*)d_out;
  float* cs = hs + HS_ELEMS;
  char* ws = (char*)d_ws;
  // ws layout (~337 MiB)
  u16* xg   = (u16*)(ws + 0);              // 256 MiB
  u16* xb   = (u16*)(ws + 268435456ull);   // 64 MiB
  u16* wihb = (u16*)(ws + 335544320ull);   // 8 MiB
  u16* whhb = (u16*)(ws + 343932928ull);   // 8 MiB
  u16* hx   = (u16*)(ws + 352321536ull);   // 512 KiB ring
  int* cnt  = (int*)(ws + 352845824ull);   // 1 KiB

  prep_kernel<<<2048, 256, 0, stream>>>(x, wih, whh, xb, wihb, whhb,
                                        (unsigned*)hx, cnt);
  gemm_xg<<<8192, 256, 0, stream>>>(xb, wihb, bias, xg);

  const u16* whhb_c = whhb; const u16* xg_c = xg;
  u16* hx_p = hx; int* cnt_p = cnt; float* hs_p = hs; float* cs_p = cs;
  void* args[6];
  args[0] = (void*)&whhb_c;
  args[1] = (void*)&xg_c;
  args[2] = (void*)&hx_p;
  args[3] = (void*)&cnt_p;
  args[4] = (void*)&hs_p;
  args[5] = (void*)&cs_p;
  hipLaunchCooperativeKernel((const void*)lstm_rec, dim3(128), dim3(512), args, 0, stream);
}

// Round 23
// 2875.249 us; speedup vs baseline: 1.1150x; 1.0488x over previous
//
#include <hip/hip_runtime.h>
#include <stdint.h>

typedef unsigned short u16;
typedef short short8 __attribute__((ext_vector_type(8)));
typedef float f32x4 __attribute__((ext_vector_type(4)));
typedef int i32x4 __attribute__((ext_vector_type(4)));
typedef unsigned long long u64;

#define NT 512
#define NH 1024
#define G4H 4096
#define HS_ELEMS 33554432ull   // 64*512*1024

static __device__ __forceinline__ u16 f2bf(float f){
  union { float f; unsigned u; } v; v.f = f;
  unsigned r = v.u + 0x7fffu + ((v.u >> 16) & 1u);   // RNE
  return (u16)(r >> 16);
}
static __device__ __forceinline__ float bf2f(u16 s){
  union { unsigned u; float f; } v; v.u = ((unsigned)s) << 16;
  return v.f;
}
static __device__ __forceinline__ void cvt8(const float* __restrict__ in, u16* __restrict__ out, int k){
  const float4* p = (const float4*)in;
  float4 a = p[2*k], b = p[2*k+1];
  short8 o;
  o[0]=(short)f2bf(a.x); o[1]=(short)f2bf(a.y); o[2]=(short)f2bf(a.z); o[3]=(short)f2bf(a.w);
  o[4]=(short)f2bf(b.x); o[5]=(short)f2bf(b.y); o[6]=(short)f2bf(b.z); o[7]=(short)f2bf(b.w);
  ((short8*)out)[k] = o;
}

// ---------------- fused prologue: cvt x/wih/whh + init ring + all counters ----------------
__global__ void prep_kernel(const float* __restrict__ x,
                            const float* __restrict__ wih,
                            const float* __restrict__ whh,
                            u16* __restrict__ xb,
                            u16* __restrict__ wihb,
                            u16* __restrict__ whhb,
                            unsigned* __restrict__ hx,
                            int* __restrict__ cnt){
  int i = blockIdx.x*blockDim.x + threadIdx.x;
  int stride = gridDim.x*blockDim.x;
  for (int k = i; k < 4194304; k += stride) cvt8(x,   xb,   k);   // 33.5M floats
  for (int k = i; k < 524288;  k += stride) cvt8(wih, wihb, k);   // 4.2M floats
  for (int k = i; k < 524288;  k += stride) cvt8(whh, whhb, k);   // 4.2M floats
  for (int k = i; k < 131072;  k += stride) hx[k] = 0u;           // 512 KiB ring zeros
  if (i < 512) cnt[i] = 0;   // [0..255] h-counters, [256..511] chunk counters
}

// ---------------- fused producer-consumer cooperative kernel ----------------
// Grid 256 x 512 threads, LDS 96 KiB => exactly 1 WG/CU (cooperative co-residency
// on 256 CUs). __launch_bounds__(512,2) -> 256 VGPR/wave budget (weight residency
// preserved for the consumer: 128 weight regs + ~104 working set).
//
// WGs 0..127  = CONSUMER: R19/R21 recurrence, byte-identical protocol, plus a
//   chunk gate at t in {0,128,256,384}: leader polls chunkcnt[t/128] >= 2048 ->
//   barrier -> ACQUIRE fence (buffer_inv kills any stale/poison xg lines in this
//   XCD's L2; weights are in regs and all h traffic is sc1, so the inv is free
//   for the recurrence). 4 gates total; production leads consumption 4x.
//
// WGs 128..255 = PRODUCER: xg = xb @ wihb^T + bias, m97-style 128^2-tile GEMM,
//   re-indexed chunk-major. Each WG = two independent 4-wave halves, each with
//   its own LDS tile buffers (barriers are WG-wide but both halves run identical
//   iteration counts in lockstep). Tile gt = it*256 + slot; chunk = gt/2048
//   (2048 tiles per 128-step t-chunk, 8 per slot). After a slot's last chunk-k
//   tile: barrier (vmcnt drain of plain C-stores) -> half-leader RELEASE fence
//   (wbl2: dirty xg lines -> L3) -> relaxed add(8) to chunkcnt[k]. Counter hits
//   2048 only when every chunk-k tile is in L3 => consumer gate is sound.
__global__ __launch_bounds__(512, 2) void lstm_fused(
    const u16* __restrict__ whh,   // whhb [4096][1024] bf16
    const u16* __restrict__ xb,    // x bf16 [32768][1024]
    const u16* __restrict__ wihb,  // w_ih bf16 [4096][1024]
    const float* __restrict__ bias,
    u16* __restrict__ xg,          // [32768][4096] bf16 (produced here)
    u16* __restrict__ hx,          // [4][4][32][64][8] bf16 ring
    int* cnt,                      // [512]: h-cnt per group at g*64; chunkcnt at 256+k*64
    float* __restrict__ hs,
    float* __restrict__ cs)
{
  __shared__ u16 lds_h[16384];     // consumer: 32 KiB group h
  __shared__ u16 plA[2][8192];     // producer: per-half A tile (128x64 bf16)
  __shared__ u16 plB[2][8192];     // producer: per-half B tile
  const int tid  = threadIdx.x;
  const int lane = tid & 63;
  const int w    = tid >> 6;          // wave 0..7
  const int bid  = blockIdx.x;
  int* ccnt = cnt + 256;              // chunk counters, 256B-spaced

  if (bid >= 128){
    // ================= PRODUCER =================
    const int pid  = bid - 128;       // 0..127
    const int half = w >> 2;          // 0..1
    const int w4   = w & 3;
    const int wr   = (w4 >> 1)*64, wc = (w4 & 1)*64;
    u16* lA = plA[half];
    u16* lB = plB[half];
    for (int it = 0; it < 32; ++it){
      const int gt     = it*256 + pid*2 + half;
      const int chunk  = gt >> 11;          // 0..3
      const int within = gt & 2047;
      const int bpan   = within >> 5;       // 0..63 (batch row)
      const int bcol   = within & 31;       // 0..31 (N tile)
      const int rowbase = bpan*512 + chunk*128;
      f32x4 acc[4][4] = {};
      const int rA0 = rowbase + w4*32;
      const int rB0 = bcol*128 + w4*32;
      for (int kt = 0; kt < 1024; kt += 64){
        const u16* gA = xb   + (size_t)(rA0 + (lane>>3))*1024 + kt + (lane&7)*8;
        const u16* gB = wihb + (size_t)(rB0 + (lane>>3))*1024 + kt + (lane&7)*8;
#pragma unroll
        for (int c = 0; c < 4; c++){
          __builtin_amdgcn_global_load_lds(
            (const __attribute__((address_space(1))) void*)(gA + (size_t)c*8*1024),
            (__attribute__((address_space(3))) void*)&lA[(w4*32 + c*8)*64], 16, 0, 0);
          __builtin_amdgcn_global_load_lds(
            (const __attribute__((address_space(1))) void*)(gB + (size_t)c*8*1024),
            (__attribute__((address_space(3))) void*)&lB[(w4*32 + c*8)*64], 16, 0, 0);
        }
        __syncthreads();
#pragma unroll
        for (int kk = 0; kk < 2; kk++){
          short8 fa[4], fb[4];
#pragma unroll
          for (int i = 0; i < 4; i++){
            fa[i] = *(const short8*)&lA[(wr + i*16 + (lane&15))*64 + kk*32 + (lane>>4)*8];
            fb[i] = *(const short8*)&lB[(wc + i*16 + (lane&15))*64 + kk*32 + (lane>>4)*8];
          }
#pragma unroll
          for (int i = 0; i < 4; i++)
#pragma unroll
            for (int jj = 0; jj < 4; jj++)
              acc[i][jj] = __builtin_amdgcn_mfma_f32_16x16x32_bf16(fa[i], fb[jj], acc[i][jj], 0,0,0);
        }
        __syncthreads();
      }
      const int mb = rowbase + wr + ((lane>>4)<<2);
      const int nb = bcol*128 + wc + (lane&15);
#pragma unroll
      for (int jj = 0; jj < 4; jj++){
        const int n = nb + jj*16;
        const float bv = bias[n];
#pragma unroll
        for (int i = 0; i < 4; i++){
#pragma unroll
          for (int reg = 0; reg < 4; reg++){
            int m = mb + i*16 + reg;
            xg[(size_t)m*G4H + n] = f2bf(acc[i][jj][reg] + bv);
          }
        }
      }
      __syncthreads();   // vmcnt(0): this WG's C-stores accepted at L2
      if ((it & 7) == 7 && (tid & 255) == 0){
        // half-leader: flush L2 -> L3, then account 8 finished chunk-k tiles
        __builtin_amdgcn_fence(__ATOMIC_RELEASE, "agent");   // wbl2
        __hip_atomic_fetch_add(ccnt + chunk*64, 8,
                               __ATOMIC_RELAXED, __HIP_MEMORY_SCOPE_AGENT);
      }
    }
    return;
  }

  // ================= CONSUMER (R19/R21, byte-identical + chunk gate) =================
  const int g    = bid >> 5;          // batch group 0..3
  const int j    = bid & 31;          // col-slice 0..31
  const int q    = (lane & 15) >> 2;  // gate type 0:i 1:f 2:g 3:o
  const int col  = j*32 + w*4 + (lane & 3);   // h column 0..1023
  const int Gr   = q*1024 + col;              // gate row 0..4095
  const int mloc = (lane >> 4) * 4;           // batch-in-group base

  // ---- weights -> regs (R6-proven; compiler parks them in AGPRs) ----
  i32x4 wq[32];
  {
    const i32x4* wp = (const i32x4*)(whh + (size_t)Gr*1024 + ((lane>>4)*8));
#pragma unroll
    for (int kk = 0; kk < 32; kk++) wq[kk] = wp[kk*4];
#pragma unroll
    for (int kk = 0; kk < 32; kk++) asm volatile("" : "+v"(wq[kk]));
  }

  float c_st[4] = {0.f,0.f,0.f,0.f};
  int* cntg = cnt + g*64;

  for (int t = 0; t < NT; t++){
    // ---- chunk gate (4 times total): xg[.., t] valid in L3, L2 stale lines killed ----
    if ((t & 127) == 0){
      if (tid == 0){
        const int k = t >> 7;
        while (__hip_atomic_load(ccnt + k*64, __ATOMIC_RELAXED, __HIP_MEMORY_SCOPE_AGENT) < 2048)
          __builtin_amdgcn_s_sleep(1);
      }
      __syncthreads();
      __builtin_amdgcn_fence(__ATOMIC_ACQUIRE, "agent");   // buffer_inv
    }
    // xg prefetch (independent of h) — hides HBM latency under the poll
    float xv[4];
#pragma unroll
    for (int reg = 0; reg < 4; reg++){
      int b = g*16 + mloc + reg;
      xv[reg] = bf2f(xg[((size_t)b*NT + t)*G4H + Gr]);
    }
    // ---- wait for h(t-1): leader relaxed poll -> barrier ----
    if (t > 0){
      if (tid == 0){
        const int need = t * 32;
        while (__hip_atomic_load(cntg, __ATOMIC_RELAXED, __HIP_MEMORY_SCOPE_AGENT) < need)
          __builtin_amdgcn_s_sleep(1);
      }
      __syncthreads();
    }
    // ---- stage h(t-1) -> LDS via sc1 atomic u64 loads (bypass stale L2) ----
    const u64* hb64 = (const u64*)(hx + ((size_t)(((t+3)&3)*4 + g)) * 16384);
#pragma unroll
    for (int k = 0; k < 8; k++){
      int W = tid + 512*k;
      u64 v = __hip_atomic_load(hb64 + W, __ATOMIC_RELAXED, __HIP_MEMORY_SCOPE_AGENT);
      *(u64*)&lds_h[W*4] = v;
    }
    __syncthreads();

    // ---- gates = xg + h @ w_hh^T : 32 builtin MFMAs ----
    f32x4 accv[4];
    accv[0] = (f32x4){xv[0], xv[1], xv[2], xv[3]};
    accv[1] = (f32x4){0.f,0.f,0.f,0.f};
    accv[2] = accv[1]; accv[3] = accv[1];
#pragma unroll
    for (int kk = 0; kk < 32; kk++){
      short8 av = *(const short8*)&lds_h[(kk*64 + lane)*8];
      short8 bv = __builtin_bit_cast(short8, wq[kk]);
      accv[kk & 3] = __builtin_amdgcn_mfma_f32_16x16x32_bf16(av, bv, accv[kk & 3], 0,0,0);
    }
    f32x4 gv = (accv[0] + accv[1]) + (accv[2] + accv[3]);

    // ---- activations; publish h, ack, signal, THEN deferred output stores ----
    u16* wbuf = hx + ((size_t)((t&3)*4 + g)) * 16384;
    float hnv[4], cnv[4];
#pragma unroll
    for (int reg = 0; reg < 4; reg++){
      float xg_ = gv[reg];
      float sig = 1.f / (1.f + __expf(-xg_));
      float th  = 1.f - 2.f / (1.f + __expf(2.f*xg_));
      float a   = (q == 2) ? th : sig;
      float v4  = __shfl_xor(a, 4);
      float v8  = __shfl_xor(a, 8);
      float v12 = __shfl_xor(a, 12);
      float iv  = (q==0)?a :(q==1)?v4:(q==2)?v8:v12;
      float fv  = (q==1)?a :(q==0)?v4:(q==3)?v8:v12;
      float gg  = (q==2)?a :(q==3)?v4:(q==0)?v8:v12;
      float ov  = (q==3)?a :(q==2)?v4:(q==1)?v8:v12;
      float cn  = fv*c_st[reg] + iv*gg;
      c_st[reg] = cn;
      float tc  = 1.f - 2.f / (1.f + __expf(2.f*cn));
      float hn  = ov * tc;
      hnv[reg] = hn; cnv[reg] = cn;
      // publish h via paired u32 sc1 atomic store (write-through to L3)
      float hp = __shfl_xor(hn, 1);          // partner column's h
      if (q == 0 && (lane & 1) == 0){
        unsigned word = (unsigned)f2bf(hn) | ((unsigned)f2bf(hp) << 16);
        int sub = ((col & 31) >> 3)*16 + (mloc + reg);
        int idx16 = ((col >> 5)*64 + sub)*8 + (col & 7);   // even
        __hip_atomic_store((unsigned*)(wbuf + idx16), word,
                           __ATOMIC_RELAXED, __HIP_MEMORY_SCOPE_AGENT);
      }
    }
    __syncthreads();   // drains ONLY the publish stores (outputs not yet issued)
    if (tid == 0)
      __hip_atomic_fetch_add(cntg, 1, __ATOMIC_RELAXED, __HIP_MEMORY_SCOPE_AGENT);
    // deferred output stores — off the signal path; acks drain next step
#pragma unroll
    for (int reg = 0; reg < 4; reg++){
      int b = g*16 + mloc + reg;
      size_t oidx = ((size_t)b*NT + t)*NH + col;
      if (q == 1) __builtin_nontemporal_store(hnv[reg], &hs[oidx]);
      if (q == 2) __builtin_nontemporal_store(cnv[reg], &cs[oidx]);
    }
  }
}

extern "C" void kernel_launch(void* const* d_in, const int* in_sizes, int n_in,
                              void* d_out, int out_size, void* d_ws, size_t ws_size,
                              hipStream_t stream){
  const float* x    = (const float*)d_in[0];
  const float* wih  = (const float*)d_in[1];
  const float* whh  = (const float*)d_in[2];
  const float* bias = (const float*)d_in[3];
  float* hs = (float*)d_out;
  float* cs = hs + HS_ELEMS;
  char* ws = (char*)d_ws;
  // ws layout (~337 MiB)
  u16* xg   = (u16*)(ws + 0);              // 256 MiB
  u16* xb   = (u16*)(ws + 268435456ull);   // 64 MiB
  u16* wihb = (u16*)(ws + 335544320ull);   // 8 MiB
  u16* whhb = (u16*)(ws + 343932928ull);   // 8 MiB
  u16* hx   = (u16*)(ws + 352321536ull);   // 512 KiB ring
  int* cnt  = (int*)(ws + 352845824ull);   // 2 KiB (h-counters + chunk counters)

  prep_kernel<<<2048, 256, 0, stream>>>(x, wih, whh, xb, wihb, whhb,
                                        (unsigned*)hx, cnt);

  const u16* whhb_c = whhb; const u16* xb_c = xb; const u16* wihb_c = wihb;
  const float* bias_c = bias;
  u16* xg_p = xg; u16* hx_p = hx; int* cnt_p = cnt;
  float* hs_p = hs; float* cs_p = cs;
  void* args[9];
  args[0] = (void*)&whhb_c;
  args[1] = (void*)&xb_c;
  args[2] = (void*)&wihb_c;
  args[3] = (void*)&bias_c;
  args[4] = (void*)&xg_p;
  args[5] = (void*)&hx_p;
  args[6] = (void*)&cnt_p;
  args[7] = (void*)&hs_p;
  args[8] = (void*)&cs_p;
  hipLaunchCooperativeKernel((const void*)lstm_fused, dim3(256), dim3(512), args, 0, stream);
}

// Round 24
// 2767.848 us; speedup vs baseline: 1.1583x; 1.0388x over previous
//
#include <hip/hip_runtime.h>
#include <stdint.h>

typedef unsigned short u16;
typedef short short8 __attribute__((ext_vector_type(8)));
typedef float f32x4 __attribute__((ext_vector_type(4)));
typedef int i32x4 __attribute__((ext_vector_type(4)));
typedef unsigned long long u64;

#define NT 512
#define NH 1024
#define G4H 4096
#define HS_ELEMS 33554432ull   // 64*512*1024

static __device__ __forceinline__ u16 f2bf(float f){
  union { float f; unsigned u; } v; v.f = f;
  unsigned r = v.u + 0x7fffu + ((v.u >> 16) & 1u);   // RNE
  return (u16)(r >> 16);
}
static __device__ __forceinline__ float bf2f(u16 s){
  union { unsigned u; float f; } v; v.u = ((unsigned)s) << 16;
  return v.f;
}
static __device__ __forceinline__ void cvt8(const float* __restrict__ in, u16* __restrict__ out, int k){
  const float4* p = (const float4*)in;
  float4 a = p[2*k], b = p[2*k+1];
  short8 o;
  o[0]=(short)f2bf(a.x); o[1]=(short)f2bf(a.y); o[2]=(short)f2bf(a.z); o[3]=(short)f2bf(a.w);
  o[4]=(short)f2bf(b.x); o[5]=(short)f2bf(b.y); o[6]=(short)f2bf(b.z); o[7]=(short)f2bf(b.w);
  ((short8*)out)[k] = o;
}

// ---------------- fused prologue: cvt x/wih/whh + init ring + all counters ----------------
__global__ void prep_kernel(const float* __restrict__ x,
                            const float* __restrict__ wih,
                            const float* __restrict__ whh,
                            u16* __restrict__ xb,
                            u16* __restrict__ wihb,
                            u16* __restrict__ whhb,
                            unsigned* __restrict__ hx,
                            int* __restrict__ cnt){
  int i = blockIdx.x*blockDim.x + threadIdx.x;
  int stride = gridDim.x*blockDim.x;
  for (int k = i; k < 4194304; k += stride) cvt8(x,   xb,   k);   // 33.5M floats
  for (int k = i; k < 524288;  k += stride) cvt8(wih, wihb, k);   // 4.2M floats
  for (int k = i; k < 524288;  k += stride) cvt8(whh, whhb, k);   // 4.2M floats
  for (int k = i; k < 131072;  k += stride) hx[k] = 0u;           // 512 KiB ring zeros
  if (i < 512) cnt[i] = 0;   // [0..255] h-counters, [256..511] chunk counters
}

// one m97-style 128^2 GEMM tile: xg[rowbase..+127][bcol*128..+127] = xb @ wihb^T + bias
static __device__ __forceinline__ void gemm_tile(
    const u16* __restrict__ xb, const u16* __restrict__ wihb,
    const float* __restrict__ bias, u16* __restrict__ xg,
    u16* lA, u16* lB, int rowbase, int bcol,
    int lane, int w4, int wr, int wc)
{
  f32x4 acc[4][4] = {};
  const int rA0 = rowbase + w4*32;
  const int rB0 = bcol*128 + w4*32;
  for (int kt = 0; kt < 1024; kt += 64){
    const u16* gA = xb   + (size_t)(rA0 + (lane>>3))*1024 + kt + (lane&7)*8;
    const u16* gB = wihb + (size_t)(rB0 + (lane>>3))*1024 + kt + (lane&7)*8;
#pragma unroll
    for (int c = 0; c < 4; c++){
      __builtin_amdgcn_global_load_lds(
        (const __attribute__((address_space(1))) void*)(gA + (size_t)c*8*1024),
        (__attribute__((address_space(3))) void*)&lA[(w4*32 + c*8)*64], 16, 0, 0);
      __builtin_amdgcn_global_load_lds(
        (const __attribute__((address_space(1))) void*)(gB + (size_t)c*8*1024),
        (__attribute__((address_space(3))) void*)&lB[(w4*32 + c*8)*64], 16, 0, 0);
    }
    __syncthreads();
#pragma unroll
    for (int kk = 0; kk < 2; kk++){
      short8 fa[4], fb[4];
#pragma unroll
      for (int i = 0; i < 4; i++){
        fa[i] = *(const short8*)&lA[(wr + i*16 + (lane&15))*64 + kk*32 + (lane>>4)*8];
        fb[i] = *(const short8*)&lB[(wc + i*16 + (lane&15))*64 + kk*32 + (lane>>4)*8];
      }
#pragma unroll
      for (int i = 0; i < 4; i++)
#pragma unroll
        for (int jj = 0; jj < 4; jj++)
          acc[i][jj] = __builtin_amdgcn_mfma_f32_16x16x32_bf16(fa[i], fb[jj], acc[i][jj], 0,0,0);
    }
    __syncthreads();
  }
  const int mb = rowbase + wr + ((lane>>4)<<2);
  const int nb = bcol*128 + wc + (lane&15);
#pragma unroll
  for (int jj = 0; jj < 4; jj++){
    const int n = nb + jj*16;
    const float bv = bias[n];
#pragma unroll
    for (int i = 0; i < 4; i++){
#pragma unroll
      for (int reg = 0; reg < 4; reg++){
        int m = mb + i*16 + reg;
        xg[(size_t)m*G4H + n] = f2bf(acc[i][jj][reg] + bv);
      }
    }
  }
}

// ---------------- fused producer-consumer cooperative kernel ----------------
// Grid 256 x 512 threads, LDS 96 KiB => 1 WG/CU. __launch_bounds__(512,2) ->
// 256 VGPR/wave budget.
// PHASE A (all 256 WGs = 512 tile-halves): produce chunk 0 (2048 tiles) in
//   4 iterations — halves the consumer's cold-start wait vs R23. Each half
//   signals add(4) to ccnt[0] after its 4th tile (512*4 = 2048), preceded by
//   the proven stores -> barrier(vmcnt drain) -> release fence (wbl2).
// PHASE B: WGs 128..255 continue as PRODUCER for chunks 1..3 (24 iterations,
//   add(8) per 8-iteration chunk block: 256*8 = 2048). WGs 0..127 become the
//   R19/R21 CONSUMER (byte-identical protocol + chunk gates at t%128==0:
//   poll ccnt[k] >= 2048 -> barrier -> acquire fence/buffer_inv; weights in
//   regs and h traffic sc1, so the inv only affects xg lines — sound).
__global__ __launch_bounds__(512, 2) void lstm_fused(
    const u16* __restrict__ whh,   // whhb [4096][1024] bf16
    const u16* __restrict__ xb,    // x bf16 [32768][1024]
    const u16* __restrict__ wihb,  // w_ih bf16 [4096][1024]
    const float* __restrict__ bias,
    u16* __restrict__ xg,          // [32768][4096] bf16 (produced here)
    u16* __restrict__ hx,          // [4][4][32][64][8] bf16 ring
    int* cnt,                      // [512]: h-cnt per group at g*64; chunkcnt at 256+k*64
    float* __restrict__ hs,
    float* __restrict__ cs)
{
  __shared__ u16 lds_h[16384];     // consumer: 32 KiB group h
  __shared__ u16 plA[2][8192];     // tile halves: A (128x64 bf16)
  __shared__ u16 plB[2][8192];     // tile halves: B
  const int tid  = threadIdx.x;
  const int lane = tid & 63;
  const int w    = tid >> 6;          // wave 0..7
  const int bid  = blockIdx.x;
  int* ccnt = cnt + 256;              // chunk counters, 256B-spaced

  const int half = w >> 2;            // 0..1
  const int w4   = w & 3;
  const int wr   = (w4 >> 1)*64, wc = (w4 & 1)*64;
  u16* lA = plA[half];
  u16* lB = plB[half];

  // ================= PHASE A: all WGs produce chunk 0 =================
  for (int it = 0; it < 4; ++it){
    const int gt     = it*512 + bid*2 + half;   // 0..2047, chunk 0
    const int within = gt & 2047;
    const int bpan   = within >> 5;             // 0..63
    const int bcol   = within & 31;             // 0..31
    gemm_tile(xb, wihb, bias, xg, lA, lB, bpan*512, bcol, lane, w4, wr, wc);
    __syncthreads();   // vmcnt(0): this WG's C-stores accepted at L2
    if (it == 3 && (tid & 255) == 0){
      __builtin_amdgcn_fence(__ATOMIC_RELEASE, "agent");   // wbl2: xg -> L3
      __hip_atomic_fetch_add(ccnt + 0, 4,
                             __ATOMIC_RELAXED, __HIP_MEMORY_SCOPE_AGENT);
    }
  }

  if (bid >= 128){
    // ================= PHASE B: PRODUCER (chunks 1..3) =================
    const int pid = bid - 128;        // 0..127
    for (int it = 0; it < 24; ++it){
      const int gt     = 2048 + it*256 + pid*2 + half;
      const int chunk  = gt >> 11;          // 1..3
      const int within = gt & 2047;
      const int bpan   = within >> 5;
      const int bcol   = within & 31;
      gemm_tile(xb, wihb, bias, xg, lA, lB, bpan*512 + chunk*128, bcol,
                lane, w4, wr, wc);
      __syncthreads();
      if ((it & 7) == 7 && (tid & 255) == 0){
        __builtin_amdgcn_fence(__ATOMIC_RELEASE, "agent");   // wbl2
        __hip_atomic_fetch_add(ccnt + chunk*64, 8,
                               __ATOMIC_RELAXED, __HIP_MEMORY_SCOPE_AGENT);
      }
    }
    return;
  }

  // ================= PHASE B: CONSUMER (R19/R21, byte-identical + chunk gate) =================
  const int g    = bid >> 5;          // batch group 0..3
  const int j    = bid & 31;          // col-slice 0..31
  const int q    = (lane & 15) >> 2;  // gate type 0:i 1:f 2:g 3:o
  const int col  = j*32 + w*4 + (lane & 3);   // h column 0..1023
  const int Gr   = q*1024 + col;              // gate row 0..4095
  const int mloc = (lane >> 4) * 4;           // batch-in-group base

  // ---- weights -> regs (loaded after the GEMM prologue; disjoint live range) ----
  i32x4 wq[32];
  {
    const i32x4* wp = (const i32x4*)(whh + (size_t)Gr*1024 + ((lane>>4)*8));
#pragma unroll
    for (int kk = 0; kk < 32; kk++) wq[kk] = wp[kk*4];
#pragma unroll
    for (int kk = 0; kk < 32; kk++) asm volatile("" : "+v"(wq[kk]));
  }

  float c_st[4] = {0.f,0.f,0.f,0.f};
  int* cntg = cnt + g*64;

  for (int t = 0; t < NT; t++){
    // ---- chunk gate (4 times total): xg[.., t] valid in L3, stale L2 killed ----
    if ((t & 127) == 0){
      if (tid == 0){
        const int k = t >> 7;
        while (__hip_atomic_load(ccnt + k*64, __ATOMIC_RELAXED, __HIP_MEMORY_SCOPE_AGENT) < 2048)
          __builtin_amdgcn_s_sleep(1);
      }
      __syncthreads();
      __builtin_amdgcn_fence(__ATOMIC_ACQUIRE, "agent");   // buffer_inv
    }
    // xg prefetch (independent of h) — hides HBM latency under the poll
    float xv[4];
#pragma unroll
    for (int reg = 0; reg < 4; reg++){
      int b = g*16 + mloc + reg;
      xv[reg] = bf2f(xg[((size_t)b*NT + t)*G4H + Gr]);
    }
    // ---- wait for h(t-1): leader relaxed poll -> barrier ----
    if (t > 0){
      if (tid == 0){
        const int need = t * 32;
        while (__hip_atomic_load(cntg, __ATOMIC_RELAXED, __HIP_MEMORY_SCOPE_AGENT) < need)
          __builtin_amdgcn_s_sleep(1);
      }
      __syncthreads();
    }
    // ---- stage h(t-1) -> LDS via sc1 atomic u64 loads (bypass stale L2) ----
    const u64* hb64 = (const u64*)(hx + ((size_t)(((t+3)&3)*4 + g)) * 16384);
#pragma unroll
    for (int k = 0; k < 8; k++){
      int W = tid + 512*k;
      u64 v = __hip_atomic_load(hb64 + W, __ATOMIC_RELAXED, __HIP_MEMORY_SCOPE_AGENT);
      *(u64*)&lds_h[W*4] = v;
    }
    __syncthreads();

    // ---- gates = xg + h @ w_hh^T : 32 builtin MFMAs ----
    f32x4 accv[4];
    accv[0] = (f32x4){xv[0], xv[1], xv[2], xv[3]};
    accv[1] = (f32x4){0.f,0.f,0.f,0.f};
    accv[2] = accv[1]; accv[3] = accv[1];
#pragma unroll
    for (int kk = 0; kk < 32; kk++){
      short8 av = *(const short8*)&lds_h[(kk*64 + lane)*8];
      short8 bv = __builtin_bit_cast(short8, wq[kk]);
      accv[kk & 3] = __builtin_amdgcn_mfma_f32_16x16x32_bf16(av, bv, accv[kk & 3], 0,0,0);
    }
    f32x4 gv = (accv[0] + accv[1]) + (accv[2] + accv[3]);

    // ---- activations; publish h, ack, signal, THEN deferred output stores ----
    u16* wbuf = hx + ((size_t)((t&3)*4 + g)) * 16384;
    float hnv[4], cnv[4];
#pragma unroll
    for (int reg = 0; reg < 4; reg++){
      float xg_ = gv[reg];
      float sig = 1.f / (1.f + __expf(-xg_));
      float th  = 1.f - 2.f / (1.f + __expf(2.f*xg_));
      float a   = (q == 2) ? th : sig;
      float v4  = __shfl_xor(a, 4);
      float v8  = __shfl_xor(a, 8);
      float v12 = __shfl_xor(a, 12);
      float iv  = (q==0)?a :(q==1)?v4:(q==2)?v8:v12;
      float fv  = (q==1)?a :(q==0)?v4:(q==3)?v8:v12;
      float gg  = (q==2)?a :(q==3)?v4:(q==0)?v8:v12;
      float ov  = (q==3)?a :(q==2)?v4:(q==1)?v8:v12;
      float cn  = fv*c_st[reg] + iv*gg;
      c_st[reg] = cn;
      float tc  = 1.f - 2.f / (1.f + __expf(2.f*cn));
      float hn  = ov * tc;
      hnv[reg] = hn; cnv[reg] = cn;
      // publish h via paired u32 sc1 atomic store (write-through to L3)
      float hp = __shfl_xor(hn, 1);          // partner column's h
      if (q == 0 && (lane & 1) == 0){
        unsigned word = (unsigned)f2bf(hn) | ((unsigned)f2bf(hp) << 16);
        int sub = ((col & 31) >> 3)*16 + (mloc + reg);
        int idx16 = ((col >> 5)*64 + sub)*8 + (col & 7);   // even
        __hip_atomic_store((unsigned*)(wbuf + idx16), word,
                           __ATOMIC_RELAXED, __HIP_MEMORY_SCOPE_AGENT);
      }
    }
    __syncthreads();   // drains ONLY the publish stores (outputs not yet issued)
    if (tid == 0)
      __hip_atomic_fetch_add(cntg, 1, __ATOMIC_RELAXED, __HIP_MEMORY_SCOPE_AGENT);
    // deferred output stores — off the signal path; acks drain next step
#pragma unroll
    for (int reg = 0; reg < 4; reg++){
      int b = g*16 + mloc + reg;
      size_t oidx = ((size_t)b*NT + t)*NH + col;
      if (q == 1) __builtin_nontemporal_store(hnv[reg], &hs[oidx]);
      if (q == 2) __builtin_nontemporal_store(cnv[reg], &cs[oidx]);
    }
  }
}

extern "C" void kernel_launch(void* const* d_in, const int* in_sizes, int n_in,
                              void* d_out, int out_size, void* d_ws, size_t ws_size,
                              hipStream_t stream){
  const float* x    = (const float*)d_in[0];
  const float* wih  = (const float*)d_in[1];
  const float* whh  = (const float*)d_in[2];
  const float* bias = (const float*)d_in[3];
  float* hs = (float*)d_out;
  float* cs = hs + HS_ELEMS;
  char* ws = (char*)d_ws;
  // ws layout (~337 MiB)
  u16* xg   = (u16*)(ws + 0);              // 256 MiB
  u16* xb   = (u16*)(ws + 268435456ull);   // 64 MiB
  u16* wihb = (u16*)(ws + 335544320ull);   // 8 MiB
  u16* whhb = (u16*)(ws + 343932928ull);   // 8 MiB
  u16* hx   = (u16*)(ws + 352321536ull);   // 512 KiB ring
  int* cnt  = (int*)(ws + 352845824ull);   // 2 KiB (h-counters + chunk counters)

  prep_kernel<<<2048, 256, 0, stream>>>(x, wih, whh, xb, wihb, whhb,
                                        (unsigned*)hx, cnt);

  const u16* whhb_c = whhb; const u16* xb_c = xb; const u16* wihb_c = wihb;
  const float* bias_c = bias;
  u16* xg_p = xg; u16* hx_p = hx; int* cnt_p = cnt;
  float* hs_p = hs; float* cs_p = cs;
  void* args[9];
  args[0] = (void*)&whhb_c;
  args[1] = (void*)&xb_c;
  args[2] = (void*)&wihb_c;
  args[3] = (void*)&bias_c;
  args[4] = (void*)&xg_p;
  args[5] = (void*)&hx_p;
  args[6] = (void*)&cnt_p;
  args[7] = (void*)&hs_p;
  args[8] = (void*)&cs_p;
  hipLaunchCooperativeKernel((const void*)lstm_fused, dim3(256), dim3(512), args, 0, stream);
}

// Round 25
// 2716.878 us; speedup vs baseline: 1.1800x; 1.0188x over previous
//
#include <hip/hip_runtime.h>
#include <stdint.h>

typedef unsigned short u16;
typedef short short8 __attribute__((ext_vector_type(8)));
typedef float f32x4 __attribute__((ext_vector_type(4)));
typedef int i32x4 __attribute__((ext_vector_type(4)));
typedef unsigned long long u64;

#define NT 512
#define NH 1024
#define G4H 4096
#define HS_ELEMS 33554432ull   // 64*512*1024

static __device__ __forceinline__ u16 f2bf(float f){
  union { float f; unsigned u; } v; v.f = f;
  unsigned r = v.u + 0x7fffu + ((v.u >> 16) & 1u);   // RNE
  return (u16)(r >> 16);
}
static __device__ __forceinline__ float bf2f(u16 s){
  union { unsigned u; float f; } v; v.u = ((unsigned)s) << 16;
  return v.f;
}
static __device__ __forceinline__ void cvt8(const float* __restrict__ in, u16* __restrict__ out, int k){
  const float4* p = (const float4*)in;
  float4 a = p[2*k], b = p[2*k+1];
  short8 o;
  o[0]=(short)f2bf(a.x); o[1]=(short)f2bf(a.y); o[2]=(short)f2bf(a.z); o[3]=(short)f2bf(a.w);
  o[4]=(short)f2bf(b.x); o[5]=(short)f2bf(b.y); o[6]=(short)f2bf(b.z); o[7]=(short)f2bf(b.w);
  ((short8*)out)[k] = o;
}

// ---------------- fused prologue: cvt x/wih/whh + init ring + all counters ----------------
__global__ void prep_kernel(const float* __restrict__ x,
                            const float* __restrict__ wih,
                            const float* __restrict__ whh,
                            u16* __restrict__ xb,
                            u16* __restrict__ wihb,
                            u16* __restrict__ whhb,
                            unsigned* __restrict__ hx,
                            int* __restrict__ cnt){
  int i = blockIdx.x*blockDim.x + threadIdx.x;
  int stride = gridDim.x*blockDim.x;
  for (int k = i; k < 4194304; k += stride) cvt8(x,   xb,   k);   // 33.5M floats
  for (int k = i; k < 524288;  k += stride) cvt8(wih, wihb, k);   // 4.2M floats
  for (int k = i; k < 524288;  k += stride) cvt8(whh, whhb, k);   // 4.2M floats
  for (int k = i; k < 131072;  k += stride) hx[k] = 0u;           // 512 KiB ring zeros
  if (i < 512) cnt[i] = 0;   // [0..255] h-counters, [256..511] chunk counters
}

// one m97-style 128^2 GEMM tile: xg[rowbase..+127][bcol*128..+127] = xb @ wihb^T + bias
static __device__ __forceinline__ void gemm_tile(
    const u16* __restrict__ xb, const u16* __restrict__ wihb,
    const float* __restrict__ bias, u16* __restrict__ xg,
    u16* lA, u16* lB, int rowbase, int bcol,
    int lane, int w4, int wr, int wc)
{
  f32x4 acc[4][4] = {};
  const int rA0 = rowbase + w4*32;
  const int rB0 = bcol*128 + w4*32;
  for (int kt = 0; kt < 1024; kt += 64){
    const u16* gA = xb   + (size_t)(rA0 + (lane>>3))*1024 + kt + (lane&7)*8;
    const u16* gB = wihb + (size_t)(rB0 + (lane>>3))*1024 + kt + (lane&7)*8;
#pragma unroll
    for (int c = 0; c < 4; c++){
      __builtin_amdgcn_global_load_lds(
        (const __attribute__((address_space(1))) void*)(gA + (size_t)c*8*1024),
        (__attribute__((address_space(3))) void*)&lA[(w4*32 + c*8)*64], 16, 0, 0);
      __builtin_amdgcn_global_load_lds(
        (const __attribute__((address_space(1))) void*)(gB + (size_t)c*8*1024),
        (__attribute__((address_space(3))) void*)&lB[(w4*32 + c*8)*64], 16, 0, 0);
    }
    __syncthreads();
#pragma unroll
    for (int kk = 0; kk < 2; kk++){
      short8 fa[4], fb[4];
#pragma unroll
      for (int i = 0; i < 4; i++){
        fa[i] = *(const short8*)&lA[(wr + i*16 + (lane&15))*64 + kk*32 + (lane>>4)*8];
        fb[i] = *(const short8*)&lB[(wc + i*16 + (lane&15))*64 + kk*32 + (lane>>4)*8];
      }
#pragma unroll
      for (int i = 0; i < 4; i++)
#pragma unroll
        for (int jj = 0; jj < 4; jj++)
          acc[i][jj] = __builtin_amdgcn_mfma_f32_16x16x32_bf16(fa[i], fb[jj], acc[i][jj], 0,0,0);
    }
    __syncthreads();
  }
  const int mb = rowbase + wr + ((lane>>4)<<2);
  const int nb = bcol*128 + wc + (lane&15);
#pragma unroll
  for (int jj = 0; jj < 4; jj++){
    const int n = nb + jj*16;
    const float bv = bias[n];
#pragma unroll
    for (int i = 0; i < 4; i++){
#pragma unroll
      for (int reg = 0; reg < 4; reg++){
        int m = mb + i*16 + reg;
        xg[(size_t)m*G4H + n] = f2bf(acc[i][jj][reg] + bv);
      }
    }
  }
}

// ---------------- fused producer-consumer cooperative kernel ----------------
// Grid 256 x 512 threads, LDS 96 KiB => 1 WG/CU. __launch_bounds__(512,2) ->
// 256 VGPR/wave budget.
// PHASE A (all 256 WGs = 512 tile-halves): produce chunk 0 (2048 tiles) in
//   4 iterations. Signal: ONE leader per WG — barrier (vmcnt drain of the
//   whole WG's C-stores) -> release fence (wbl2) -> add(8) (2 halves x 4
//   tiles; 256 x 8 = 2048). Half the fences of R24.
// PHASE B: WGs 128..255 PRODUCER, chunks 1..3 (24 iterations). Barrier ONLY
//   on signal iterations (it&7==7; LDS reuse is already protected by the
//   K-loop's trailing barrier inside gemm_tile). Signal per WG: fence +
//   add(16) (2 halves x 8 tiles; 128 x 16 = 2048 per chunk).
// WGs 0..127 = CONSUMER: R19/R21 recurrence byte-identical + chunk gates at
//   t%128==0 (poll ccnt[k]>=2048 -> barrier -> acquire fence/buffer_inv).
__global__ __launch_bounds__(512, 2) void lstm_fused(
    const u16* __restrict__ whh,   // whhb [4096][1024] bf16
    const u16* __restrict__ xb,    // x bf16 [32768][1024]
    const u16* __restrict__ wihb,  // w_ih bf16 [4096][1024]
    const float* __restrict__ bias,
    u16* __restrict__ xg,          // [32768][4096] bf16 (produced here)
    u16* __restrict__ hx,          // [4][4][32][64][8] bf16 ring
    int* cnt,                      // [512]: h-cnt per group at g*64; chunkcnt at 256+k*64
    float* __restrict__ hs,
    float* __restrict__ cs)
{
  __shared__ u16 lds_h[16384];     // consumer: 32 KiB group h
  __shared__ u16 plA[2][8192];     // tile halves: A (128x64 bf16)
  __shared__ u16 plB[2][8192];     // tile halves: B
  const int tid  = threadIdx.x;
  const int lane = tid & 63;
  const int w    = tid >> 6;          // wave 0..7
  const int bid  = blockIdx.x;
  int* ccnt = cnt + 256;              // chunk counters, 256B-spaced

  const int half = w >> 2;            // 0..1
  const int w4   = w & 3;
  const int wr   = (w4 >> 1)*64, wc = (w4 & 1)*64;
  u16* lA = plA[half];
  u16* lB = plB[half];

  // ================= PHASE A: all WGs produce chunk 0 =================
  for (int it = 0; it < 4; ++it){
    const int gt     = it*512 + bid*2 + half;   // 0..2047, chunk 0
    const int within = gt & 2047;
    const int bpan   = within >> 5;             // 0..63
    const int bcol   = within & 31;             // 0..31
    gemm_tile(xb, wihb, bias, xg, lA, lB, bpan*512, bcol, lane, w4, wr, wc);
    if (it == 3){
      __syncthreads();   // vmcnt(0): whole WG's C-stores accepted at L2
      if (tid == 0){
        __builtin_amdgcn_fence(__ATOMIC_RELEASE, "agent");   // wbl2: xg -> L3
        __hip_atomic_fetch_add(ccnt + 0, 8,
                               __ATOMIC_RELAXED, __HIP_MEMORY_SCOPE_AGENT);
      }
    }
  }

  if (bid >= 128){
    // ================= PHASE B: PRODUCER (chunks 1..3) =================
    const int pid = bid - 128;        // 0..127
    for (int it = 0; it < 24; ++it){
      const int gt     = 2048 + it*256 + pid*2 + half;
      const int chunk  = gt >> 11;          // 1..3
      const int within = gt & 2047;
      const int bpan   = within >> 5;
      const int bcol   = within & 31;
      gemm_tile(xb, wihb, bias, xg, lA, lB, bpan*512 + chunk*128, bcol,
                lane, w4, wr, wc);
      if ((it & 7) == 7){
        __syncthreads();   // drain the 8-iteration block's C-stores
        if (tid == 0){
          __builtin_amdgcn_fence(__ATOMIC_RELEASE, "agent");   // wbl2
          __hip_atomic_fetch_add(ccnt + chunk*64, 16,
                                 __ATOMIC_RELAXED, __HIP_MEMORY_SCOPE_AGENT);
        }
      }
    }
    return;
  }

  // ================= PHASE B: CONSUMER (R19/R21, byte-identical + chunk gate) =================
  const int g    = bid >> 5;          // batch group 0..3
  const int j    = bid & 31;          // col-slice 0..31
  const int q    = (lane & 15) >> 2;  // gate type 0:i 1:f 2:g 3:o
  const int col  = j*32 + w*4 + (lane & 3);   // h column 0..1023
  const int Gr   = q*1024 + col;              // gate row 0..4095
  const int mloc = (lane >> 4) * 4;           // batch-in-group base

  // ---- weights -> regs (loaded after the GEMM prologue; disjoint live range) ----
  i32x4 wq[32];
  {
    const i32x4* wp = (const i32x4*)(whh + (size_t)Gr*1024 + ((lane>>4)*8));
#pragma unroll
    for (int kk = 0; kk < 32; kk++) wq[kk] = wp[kk*4];
#pragma unroll
    for (int kk = 0; kk < 32; kk++) asm volatile("" : "+v"(wq[kk]));
  }

  float c_st[4] = {0.f,0.f,0.f,0.f};
  int* cntg = cnt + g*64;

  for (int t = 0; t < NT; t++){
    // ---- chunk gate (4 times total): xg[.., t] valid in L3, stale L2 killed ----
    if ((t & 127) == 0){
      if (tid == 0){
        const int k = t >> 7;
        while (__hip_atomic_load(ccnt + k*64, __ATOMIC_RELAXED, __HIP_MEMORY_SCOPE_AGENT) < 2048)
          __builtin_amdgcn_s_sleep(1);
      }
      __syncthreads();
      __builtin_amdgcn_fence(__ATOMIC_ACQUIRE, "agent");   // buffer_inv
    }
    // xg prefetch (independent of h) — hides HBM latency under the poll
    float xv[4];
#pragma unroll
    for (int reg = 0; reg < 4; reg++){
      int b = g*16 + mloc + reg;
      xv[reg] = bf2f(xg[((size_t)b*NT + t)*G4H + Gr]);
    }
    // ---- wait for h(t-1): leader relaxed poll -> barrier ----
    if (t > 0){
      if (tid == 0){
        const int need = t * 32;
        while (__hip_atomic_load(cntg, __ATOMIC_RELAXED, __HIP_MEMORY_SCOPE_AGENT) < need)
          __builtin_amdgcn_s_sleep(1);
      }
      __syncthreads();
    }
    // ---- stage h(t-1) -> LDS via sc1 atomic u64 loads (bypass stale L2) ----
    const u64* hb64 = (const u64*)(hx + ((size_t)(((t+3)&3)*4 + g)) * 16384);
#pragma unroll
    for (int k = 0; k < 8; k++){
      int W = tid + 512*k;
      u64 v = __hip_atomic_load(hb64 + W, __ATOMIC_RELAXED, __HIP_MEMORY_SCOPE_AGENT);
      *(u64*)&lds_h[W*4] = v;
    }
    __syncthreads();

    // ---- gates = xg + h @ w_hh^T : 32 builtin MFMAs ----
    f32x4 accv[4];
    accv[0] = (f32x4){xv[0], xv[1], xv[2], xv[3]};
    accv[1] = (f32x4){0.f,0.f,0.f,0.f};
    accv[2] = accv[1]; accv[3] = accv[1];
#pragma unroll
    for (int kk = 0; kk < 32; kk++){
      short8 av = *(const short8*)&lds_h[(kk*64 + lane)*8];
      short8 bv = __builtin_bit_cast(short8, wq[kk]);
      accv[kk & 3] = __builtin_amdgcn_mfma_f32_16x16x32_bf16(av, bv, accv[kk & 3], 0,0,0);
    }
    f32x4 gv = (accv[0] + accv[1]) + (accv[2] + accv[3]);

    // ---- activations; publish h, ack, signal, THEN deferred output stores ----
    u16* wbuf = hx + ((size_t)((t&3)*4 + g)) * 16384;
    float hnv[4], cnv[4];
#pragma unroll
    for (int reg = 0; reg < 4; reg++){
      float xg_ = gv[reg];
      float sig = 1.f / (1.f + __expf(-xg_));
      float th  = 1.f - 2.f / (1.f + __expf(2.f*xg_));
      float a   = (q == 2) ? th : sig;
      float v4  = __shfl_xor(a, 4);
      float v8  = __shfl_xor(a, 8);
      float v12 = __shfl_xor(a, 12);
      float iv  = (q==0)?a :(q==1)?v4:(q==2)?v8:v12;
      float fv  = (q==1)?a :(q==0)?v4:(q==3)?v8:v12;
      float gg  = (q==2)?a :(q==3)?v4:(q==0)?v8:v12;
      float ov  = (q==3)?a :(q==2)?v4:(q==1)?v8:v12;
      float cn  = fv*c_st[reg] + iv*gg;
      c_st[reg] = cn;
      float tc  = 1.f - 2.f / (1.f + __expf(2.f*cn));
      float hn  = ov * tc;
      hnv[reg] = hn; cnv[reg] = cn;
      // publish h via paired u32 sc1 atomic store (write-through to L3)
      float hp = __shfl_xor(hn, 1);          // partner column's h
      if (q == 0 && (lane & 1) == 0){
        unsigned word = (unsigned)f2bf(hn) | ((unsigned)f2bf(hp) << 16);
        int sub = ((col & 31) >> 3)*16 + (mloc + reg);
        int idx16 = ((col >> 5)*64 + sub)*8 + (col & 7);   // even
        __hip_atomic_store((unsigned*)(wbuf + idx16), word,
                           __ATOMIC_RELAXED, __HIP_MEMORY_SCOPE_AGENT);
      }
    }
    __syncthreads();   // drains ONLY the publish stores (outputs not yet issued)
    if (tid == 0)
      __hip_atomic_fetch_add(cntg, 1, __ATOMIC_RELAXED, __HIP_MEMORY_SCOPE_AGENT);
    // deferred output stores — off the signal path; acks drain next step
#pragma unroll
    for (int reg = 0; reg < 4; reg++){
      int b = g*16 + mloc + reg;
      size_t oidx = ((size_t)b*NT + t)*NH + col;
      if (q == 1) __builtin_nontemporal_store(hnv[reg], &hs[oidx]);
      if (q == 2) __builtin_nontemporal_store(cnv[reg], &cs[oidx]);
    }
  }
}

extern "C" void kernel_launch(void* const* d_in, const int* in_sizes, int n_in,
                              void* d_out, int out_size, void* d_ws, size_t ws_size,
                              hipStream_t stream){
  const float* x    = (const float*)d_in[0];
  const float* wih  = (const float*)d_in[1];
  const float* whh  = (const float*)d_in[2];
  const float* bias = (const float*)d_in[3];
  float* hs = (float*)d_out;
  float* cs = hs + HS_ELEMS;
  char* ws = (char*)d_ws;
  // ws layout (~337 MiB)
  u16* xg   = (u16*)(ws + 0);              // 256 MiB
  u16* xb   = (u16*)(ws + 268435456ull);   // 64 MiB
  u16* wihb = (u16*)(ws + 335544320ull);   // 8 MiB
  u16* whhb = (u16*)(ws + 343932928ull);   // 8 MiB
  u16* hx   = (u16*)(ws + 352321536ull);   // 512 KiB ring
  int* cnt  = (int*)(ws + 352845824ull);   // 2 KiB (h-counters + chunk counters)

  prep_kernel<<<2048, 256, 0, stream>>>(x, wih, whh, xb, wihb, whhb,
                                        (unsigned*)hx, cnt);

  const u16* whhb_c = whhb; const u16* xb_c = xb; const u16* wihb_c = wihb;
  const float* bias_c = bias;
  u16* xg_p = xg; u16* hx_p = hx; int* cnt_p = cnt;
  float* hs_p = hs; float* cs_p = cs;
  void* args[9];
  args[0] = (void*)&whhb_c;
  args[1] = (void*)&xb_c;
  args[2] = (void*)&wihb_c;
  args[3] = (void*)&bias_c;
  args[4] = (void*)&xg_p;
  args[5] = (void*)&hx_p;
  args[6] = (void*)&cnt_p;
  args[7] = (void*)&hs_p;
  args[8] = (void*)&cs_p;
  hipLaunchCooperativeKernel((const void*)lstm_fused, dim3(256), dim3(512), args, 0, stream);
}